// Round 4
// baseline (263.434 us; speedup 1.0000x reference)
//
#include <hip/hip_runtime.h>

// TELIF: temporal-encoding LIF neuron scan.
// tx: [T,B,N] fp32, TE: [N,T] fp32, out: [T,B,N] fp32. T=512,B=64,N=1024.
// One thread per (b,n); sequential over t. 65536 threads = 4 waves/CU.
//
// R1/R2 post-mortem: 16-step chunk cost ~17.5K cy == ~20 serialized HBM
// latencies == one per load -> prefetch arrays landed in scratch (SROA
// defeated), forcing waitcnt vmcnt(0) per load. R3/R4: NO arrays, NO
// lambdas — double-buffer in named float4 registers, hand-unrolled macros.
// (R3 compile fix: `r##0 .x` — `0.x` lexes as one pp-number token, so the
// paste must target the bare digit.)

#define T_STEPS 512
#define BN      (64 * 1024)

#define NTL(i)  __builtin_nontemporal_load(txp + (size_t)(i) * BN)
#define LD4(i)  (*reinterpret_cast<const float4*>(tep + (i)))

// Prefetch 16 tx values (stride BN) into 4 named float4s.
#define PFX(r, base) \
  r##0 .x = NTL((base)+0);  r##0 .y = NTL((base)+1);  r##0 .z = NTL((base)+2);  r##0 .w = NTL((base)+3);  \
  r##1 .x = NTL((base)+4);  r##1 .y = NTL((base)+5);  r##1 .z = NTL((base)+6);  r##1 .w = NTL((base)+7);  \
  r##2 .x = NTL((base)+8);  r##2 .y = NTL((base)+9);  r##2 .z = NTL((base)+10); r##2 .w = NTL((base)+11); \
  r##3 .x = NTL((base)+12); r##3 .y = NTL((base)+13); r##3 .z = NTL((base)+14); r##3 .w = NTL((base)+15);

// Prefetch 16 contiguous TE values into 4 named float4s.
#define PFE(r, base) \
  r##0 = LD4((base)+0); r##1 = LD4((base)+4); r##2 = LD4((base)+8); r##3 = LD4((base)+12);

// One LIF step, exact reference op order (fp contract off):
//   th = th + v*te - (th-THRESHOLD)*BETA ; v = v*DECAY*(1-y) + x ; y = (v>th)
#define STEP1(xv, tv, tt) { \
  float A_ = v * (tv); float B_ = th + A_; float C_ = th - 0.3f; \
  float D_ = C_ * 0.02f; th = B_ - D_; \
  float E_ = v * 0.2f; float F_ = 1.0f - y; float G_ = E_ * F_; \
  v = G_ + (xv); y = (v > th) ? 1.0f : 0.0f; \
  __builtin_nontemporal_store(y, outp + (size_t)(tt) * BN); }

#define COMP(r, s, base) \
  STEP1(r##0 .x, s##0 .x, (base)+0)  STEP1(r##0 .y, s##0 .y, (base)+1)  \
  STEP1(r##0 .z, s##0 .z, (base)+2)  STEP1(r##0 .w, s##0 .w, (base)+3)  \
  STEP1(r##1 .x, s##1 .x, (base)+4)  STEP1(r##1 .y, s##1 .y, (base)+5)  \
  STEP1(r##1 .z, s##1 .z, (base)+6)  STEP1(r##1 .w, s##1 .w, (base)+7)  \
  STEP1(r##2 .x, s##2 .x, (base)+8)  STEP1(r##2 .y, s##2 .y, (base)+9)  \
  STEP1(r##2 .z, s##2 .z, (base)+10) STEP1(r##2 .w, s##2 .w, (base)+11) \
  STEP1(r##3 .x, s##3 .x, (base)+12) STEP1(r##3 .y, s##3 .y, (base)+13) \
  STEP1(r##3 .z, s##3 .z, (base)+14) STEP1(r##3 .w, s##3 .w, (base)+15)

__global__ __launch_bounds__(256, 1) void telif_kernel(
    const float* __restrict__ tx, const float* __restrict__ TE,
    float* __restrict__ out)
{
#pragma clang fp contract(off)

    const int flat = blockIdx.x * 256 + threadIdx.x;   // b*N + n
    const int n = flat & 1023;

    const float* txp  = tx + flat;          // stride BN over t, coalesced across lanes
    const float* tep  = TE + n * T_STEPS;   // contiguous over t per thread
    float*       outp = out + flat;

    float v = 0.0f, y = 0.0f, th = 0.3f;

    // Double buffer: chunk A (a*/e*) and chunk B (b*/f*), 16 steps each.
    float4 a0, a1, a2, a3, e0, e1, e2, e3;
    float4 b0, b1, b2, b3, f0, f1, f2, f3;

    PFX(a, 0) PFE(e, 0)

#pragma unroll 1
    for (int t = 0; t < 480; t += 32) {
        PFX(b, t + 16) PFE(f, t + 16)
        COMP(a, e, t)
        PFX(a, t + 32) PFE(e, t + 32)
        COMP(b, f, t + 16)
    }
    // Tail: chunk A holds t=480; prefetch and compute t=496.
    PFX(b, 496) PFE(f, 496)
    COMP(a, e, 480)
    COMP(b, f, 496)
}

extern "C" void kernel_launch(void* const* d_in, const int* in_sizes, int n_in,
                              void* d_out, int out_size, void* d_ws, size_t ws_size,
                              hipStream_t stream) {
    const float* tx = (const float*)d_in[0];  // [T, B, N]
    const float* TE = (const float*)d_in[1];  // [N, T]
    float* out = (float*)d_out;               // [T, B, N]
    telif_kernel<<<BN / 256, 256, 0, stream>>>(tx, TE, out);
}

// Round 5
// 233.624 us; speedup vs baseline: 1.1276x; 1.1276x over previous
//
#include <hip/hip_runtime.h>

// TELIF: temporal-encoding LIF neuron scan.
// tx: [T,B,N] fp32, TE: [N,T] fp32, out: [T,B,N] fp32. T=512,B=64,N=1024.
// One thread per (b,n); sequential over t. 65536 threads = 4 waves/CU
// (grid-capped occupancy) -> all latency hiding is intra-wave ILP.
//
// R4 post-mortem: named-reg double buffer WITHOUT scheduling pins let the
// backend sink every load to its use (VGPR_Count=68!), serializing ~300-400cy
// of MALL/HBM latency per step group -> 92 us. R2 (<=80 us) differed only in
// sched_barrier(0) pins. R5 = named float4 quad-buffer (scratch-proof) +
// 32-step lookahead + sched_barrier(0) after each prefetch burst.

#define T_STEPS 512
#define BN      (64 * 1024)

#define NTL(i)  __builtin_nontemporal_load(txp + (size_t)(i) * BN)
#define LD4(i)  (*reinterpret_cast<const float4*>(tep + (i)))

// Prefetch 16 tx values (stride BN) into 4 named float4s.
#define PFX(r, base) \
  r##0 .x = NTL((base)+0);  r##0 .y = NTL((base)+1);  r##0 .z = NTL((base)+2);  r##0 .w = NTL((base)+3);  \
  r##1 .x = NTL((base)+4);  r##1 .y = NTL((base)+5);  r##1 .z = NTL((base)+6);  r##1 .w = NTL((base)+7);  \
  r##2 .x = NTL((base)+8);  r##2 .y = NTL((base)+9);  r##2 .z = NTL((base)+10); r##2 .w = NTL((base)+11); \
  r##3 .x = NTL((base)+12); r##3 .y = NTL((base)+13); r##3 .z = NTL((base)+14); r##3 .w = NTL((base)+15);

// Prefetch 16 contiguous TE values into 4 named float4s.
#define PFE(r, base) \
  r##0 = LD4((base)+0); r##1 = LD4((base)+4); r##2 = LD4((base)+8); r##3 = LD4((base)+12);

// One LIF step, exact reference op order (fp contract off):
//   th = th + v*te - (th-THRESHOLD)*BETA ; v = v*DECAY*(1-y) + x ; y = (v>th)
#define STEP1(xv, tv, tt) { \
  float A_ = v * (tv); float B_ = th + A_; float C_ = th - 0.3f; \
  float D_ = C_ * 0.02f; th = B_ - D_; \
  float E_ = v * 0.2f; float F_ = 1.0f - y; float G_ = E_ * F_; \
  v = G_ + (xv); y = (v > th) ? 1.0f : 0.0f; \
  __builtin_nontemporal_store(y, outp + (size_t)(tt) * BN); }

#define COMP(r, s, base) \
  STEP1(r##0 .x, s##0 .x, (base)+0)  STEP1(r##0 .y, s##0 .y, (base)+1)  \
  STEP1(r##0 .z, s##0 .z, (base)+2)  STEP1(r##0 .w, s##0 .w, (base)+3)  \
  STEP1(r##1 .x, s##1 .x, (base)+4)  STEP1(r##1 .y, s##1 .y, (base)+5)  \
  STEP1(r##1 .z, s##1 .z, (base)+6)  STEP1(r##1 .w, s##1 .w, (base)+7)  \
  STEP1(r##2 .x, s##2 .x, (base)+8)  STEP1(r##2 .y, s##2 .y, (base)+9)  \
  STEP1(r##2 .z, s##2 .z, (base)+10) STEP1(r##2 .w, s##2 .w, (base)+11) \
  STEP1(r##3 .x, s##3 .x, (base)+12) STEP1(r##3 .y, s##3 .y, (base)+13) \
  STEP1(r##3 .z, s##3 .z, (base)+14) STEP1(r##3 .w, s##3 .w, (base)+15)

#define PIN() __builtin_amdgcn_sched_barrier(0)

__global__ __launch_bounds__(256, 1) void telif_kernel(
    const float* __restrict__ tx, const float* __restrict__ TE,
    float* __restrict__ out)
{
#pragma clang fp contract(off)

    const int flat = blockIdx.x * 256 + threadIdx.x;   // b*N + n
    const int n = flat & 1023;

    const float* txp  = tx + flat;          // stride BN over t, coalesced across lanes
    const float* tep  = TE + n * T_STEPS;   // contiguous over t per thread
    float*       outp = out + flat;

    float v = 0.0f, y = 0.0f, th = 0.3f;

    // Quad buffer: chunks A/B/C/D of 16 steps each; 32-step lookahead.
    float4 a0, a1, a2, a3, e0, e1, e2, e3;
    float4 b0, b1, b2, b3, f0, f1, f2, f3;
    float4 c0, c1, c2, c3, g0, g1, g2, g3;
    float4 d0, d1, d2, d3, h0, h1, h2, h3;

    PFX(a, 0)  PFE(e, 0)
    PFX(b, 16) PFE(f, 16)
    PIN();

#pragma unroll 1
    for (int t = 0; t < 448; t += 64) {
        PFX(c, t + 32) PFE(g, t + 32)
        PFX(d, t + 48) PFE(h, t + 48)
        PIN();                              // loads stay ABOVE the compute
        COMP(a, e, t)
        COMP(b, f, t + 16)
        PIN();
        PFX(a, t + 64) PFE(e, t + 64)
        PFX(b, t + 80) PFE(f, t + 80)
        PIN();
        COMP(c, g, t + 32)
        COMP(d, h, t + 48)
        PIN();
    }
    // Tail: A=448, B=464 already in registers; fetch 480/496 and finish.
    PFX(c, 480) PFE(g, 480)
    PFX(d, 496) PFE(h, 496)
    PIN();
    COMP(a, e, 448)
    COMP(b, f, 464)
    COMP(c, g, 480)
    COMP(d, h, 496)
}

extern "C" void kernel_launch(void* const* d_in, const int* in_sizes, int n_in,
                              void* d_out, int out_size, void* d_ws, size_t ws_size,
                              hipStream_t stream) {
    const float* tx = (const float*)d_in[0];  // [T, B, N]
    const float* TE = (const float*)d_in[1];  // [N, T]
    float* out = (float*)d_out;               // [T, B, N]
    telif_kernel<<<BN / 256, 256, 0, stream>>>(tx, TE, out);
}